// Round 1
// baseline (255.192 us; speedup 1.0000x reference)
//
#include <hip/hip_runtime.h>

// EMA h_t = 0.1*y_t + 0.9*h_{t-1} over (B=4, S=4096, D=2048) fp32.
// R5: counters showed latency serialization (VGPR=36 -> pipeline re-rolled,
// hbm 2.7 TB/s == 64K threads x 1 load x 16B / 375ns, occupancy 9.8%).
// Two fixes: (a) L=128->32 => 1024 blocks = 4 blocks/CU (TLP: 4.2 MB in
// flight even if compiler serializes); (b) explicit two-group double buffer
// (A consumed+stored while B's 8 loads are in flight) so the compiler cannot
// legally shrink below ~70 live VGPRs. Warm-up clamped to min(W, sm): chunk 1
// becomes exact, chunks >=2 keep 0.9^64 ~ 1.2e-3 truncation (abs thr 2.6e-2).

typedef float v4 __attribute__((ext_vector_type(4)));

constexpr int B  = 4;
constexpr int S  = 4096;
constexpr int D  = 2048;
constexpr int D4 = D / 4;     // 512 vec4 lanes per row
constexpr int L  = 32;        // chunk length  (S/L = 128 chunks)
constexpr int W  = 64;        // max warm-up window (0.9^64 ~ 1.2e-3)

__global__ __launch_bounds__(256, 4) void ema_kernel(const v4* __restrict__ y,
                                                     v4* __restrict__ out) {
    const int d4 = blockIdx.x * blockDim.x + threadIdx.x;   // 0..D4-1
    const int c  = blockIdx.y;                              // chunk
    const int b  = blockIdx.z;

    const long long base = (long long)b * S * D4 + d4;
    const int sm = c * L;                                   // first stored step

    v4 h = (v4)(0.0f);
    const v4* __restrict__ p;

    v4 a0, a1, a2, a3, a4, a5, a6, a7;
    v4 b0, b1, b2, b3, b4, b5, b6, b7;

#define LOADA() do {               \
        a0 = p[0 * D4];            \
        a1 = p[1 * D4];            \
        a2 = p[2 * D4];            \
        a3 = p[3 * D4];            \
        a4 = p[4 * D4];            \
        a5 = p[5 * D4];            \
        a6 = p[6 * D4];            \
        a7 = p[7 * D4];            \
        p += 8 * D4;               \
    } while (0)

#define LOADB() do {               \
        b0 = p[0 * D4];            \
        b1 = p[1 * D4];            \
        b2 = p[2 * D4];            \
        b3 = p[3 * D4];            \
        b4 = p[4 * D4];            \
        b5 = p[5 * D4];            \
        b6 = p[6 * D4];            \
        b7 = p[7 * D4];            \
        p += 8 * D4;               \
    } while (0)

#define EMA(x) (h = 0.9f * h + 0.1f * (x))
#define EMAA() do { EMA(a0); EMA(a1); EMA(a2); EMA(a3); \
                    EMA(a4); EMA(a5); EMA(a6); EMA(a7); } while (0)
#define EMAB() do { EMA(b0); EMA(b1); EMA(b2); EMA(b3); \
                    EMA(b4); EMA(b5); EMA(b6); EMA(b7); } while (0)

    // ---- warm-up: nw = min(W, sm) steps, no stores, double-buffered ----
    // nw is 0 (c==0), 32 (c==1, exact from t=0), or 64 (c>=2, truncated).
    const int nw = (sm < W) ? sm : W;
    p = y + base + (long long)(sm - nw) * D4;

    if (nw) {
        LOADA();                         // 8 steps in flight
        LOADB();                         // 16 in flight
        #pragma unroll 1
        for (int g = 0; g < (nw / 8 - 2) / 2; ++g) {
            EMAA(); LOADA();             // consume A while B in flight
            EMAB(); LOADB();
        }
        EMAA();
        EMAB();
    }

    // ---- main: L = 32 stored steps (groups A,B,A,B), double-buffered ----
    v4* __restrict__ q = out + base + (long long)sm * D4;

    LOADA();                             // steps sm+0 .. sm+7
    LOADB();                             // steps sm+8 .. sm+15

    EMA(a0); __builtin_nontemporal_store(h, q + 0 * D4);
    EMA(a1); __builtin_nontemporal_store(h, q + 1 * D4);
    EMA(a2); __builtin_nontemporal_store(h, q + 2 * D4);
    EMA(a3); __builtin_nontemporal_store(h, q + 3 * D4);
    EMA(a4); __builtin_nontemporal_store(h, q + 4 * D4);
    EMA(a5); __builtin_nontemporal_store(h, q + 5 * D4);
    EMA(a6); __builtin_nontemporal_store(h, q + 6 * D4);
    EMA(a7); __builtin_nontemporal_store(h, q + 7 * D4);
    LOADA();                             // steps sm+16 .. sm+23

    EMA(b0); __builtin_nontemporal_store(h, q +  8 * D4);
    EMA(b1); __builtin_nontemporal_store(h, q +  9 * D4);
    EMA(b2); __builtin_nontemporal_store(h, q + 10 * D4);
    EMA(b3); __builtin_nontemporal_store(h, q + 11 * D4);
    EMA(b4); __builtin_nontemporal_store(h, q + 12 * D4);
    EMA(b5); __builtin_nontemporal_store(h, q + 13 * D4);
    EMA(b6); __builtin_nontemporal_store(h, q + 14 * D4);
    EMA(b7); __builtin_nontemporal_store(h, q + 15 * D4);
    LOADB();                             // steps sm+24 .. sm+31

    EMA(a0); __builtin_nontemporal_store(h, q + 16 * D4);
    EMA(a1); __builtin_nontemporal_store(h, q + 17 * D4);
    EMA(a2); __builtin_nontemporal_store(h, q + 18 * D4);
    EMA(a3); __builtin_nontemporal_store(h, q + 19 * D4);
    EMA(a4); __builtin_nontemporal_store(h, q + 20 * D4);
    EMA(a5); __builtin_nontemporal_store(h, q + 21 * D4);
    EMA(a6); __builtin_nontemporal_store(h, q + 22 * D4);
    EMA(a7); __builtin_nontemporal_store(h, q + 23 * D4);

    EMA(b0); __builtin_nontemporal_store(h, q + 24 * D4);
    EMA(b1); __builtin_nontemporal_store(h, q + 25 * D4);
    EMA(b2); __builtin_nontemporal_store(h, q + 26 * D4);
    EMA(b3); __builtin_nontemporal_store(h, q + 27 * D4);
    EMA(b4); __builtin_nontemporal_store(h, q + 28 * D4);
    EMA(b5); __builtin_nontemporal_store(h, q + 29 * D4);
    EMA(b6); __builtin_nontemporal_store(h, q + 30 * D4);
    EMA(b7); __builtin_nontemporal_store(h, q + 31 * D4);

#undef EMAB
#undef EMAA
#undef EMA
#undef LOADB
#undef LOADA
}

extern "C" void kernel_launch(void* const* d_in, const int* in_sizes, int n_in,
                              void* d_out, int out_size, void* d_ws, size_t ws_size,
                              hipStream_t stream) {
    const v4* y = (const v4*)d_in[0];
    v4* out = (v4*)d_out;

    dim3 block(256, 1, 1);
    dim3 grid(D4 / 256, S / L, B);   // (2, 128, 4) = 1024 blocks, 4/CU
    ema_kernel<<<grid, block, 0, stream>>>(y, out);
}

// Round 2
// 237.039 us; speedup vs baseline: 1.0766x; 1.0766x over previous
//
#include <hip/hip_runtime.h>

// EMA h_t = 0.1*y_t + 0.9*h_{t-1} over (B=4, S=4096, D=2048) fp32.
// R5 post-mortem: VGPR=36 AGAIN -> machine scheduler re-rolled the explicit
// A/B double buffer (legal: EMA chain consumes groups in order, so it sinks
// each load to its use to save registers). L=32 also tripled read redundancy
// (FETCH 97->195 MB, L3 absorbed only half). R6: revert to L=128 (1.5x read
// redundancy) and pin the schedule with __builtin_amdgcn_sched_barrier(0)
// after every load group / consume group. The 16 buffer regs are then live
// across a scheduling fence -> allocator must keep them -> 8-16 x 16B loads
// in flight per thread. 64K threads x 8 x 16B = 8 MB in flight > 2.4 MB
// (BW x latency) -> BW-bound. Watch VGPR_Count: ~36 means the fence failed.

typedef float v4 __attribute__((ext_vector_type(4)));

constexpr int B  = 4;
constexpr int S  = 4096;
constexpr int D  = 2048;
constexpr int D4 = D / 4;     // 512 vec4 lanes per row
constexpr int L  = 128;       // chunk length  (S/L = 32 chunks)
constexpr int W  = 64;        // warm-up window (0.9^64 ~ 1.2e-3, thr 2.6e-2)

#define SB() __builtin_amdgcn_sched_barrier(0)

__global__ __launch_bounds__(256, 1) void ema_kernel(const v4* __restrict__ y,
                                                     v4* __restrict__ out) {
    const int d4 = blockIdx.x * blockDim.x + threadIdx.x;   // 0..D4-1
    const int c  = blockIdx.y;                              // chunk
    const int b  = blockIdx.z;

    const long long base = (long long)b * S * D4 + d4;
    const int sm = c * L;                                   // first stored step

    v4 h = (v4)(0.0f);
    const v4* p;

    v4 a0, a1, a2, a3, a4, a5, a6, a7;
    v4 b0, b1, b2, b3, b4, b5, b6, b7;

#define LOADA() do {               \
        a0 = p[0 * D4];            \
        a1 = p[1 * D4];            \
        a2 = p[2 * D4];            \
        a3 = p[3 * D4];            \
        a4 = p[4 * D4];            \
        a5 = p[5 * D4];            \
        a6 = p[6 * D4];            \
        a7 = p[7 * D4];            \
        p += 8 * D4;               \
    } while (0)

#define LOADB() do {               \
        b0 = p[0 * D4];            \
        b1 = p[1 * D4];            \
        b2 = p[2 * D4];            \
        b3 = p[3 * D4];            \
        b4 = p[4 * D4];            \
        b5 = p[5 * D4];            \
        b6 = p[6 * D4];            \
        b7 = p[7 * D4];            \
        p += 8 * D4;               \
    } while (0)

#define EMA(x) (h = 0.9f * h + 0.1f * (x))
#define EMAA() do { EMA(a0); EMA(a1); EMA(a2); EMA(a3); \
                    EMA(a4); EMA(a5); EMA(a6); EMA(a7); } while (0)
#define EMAB() do { EMA(b0); EMA(b1); EMA(b2); EMA(b3); \
                    EMA(b4); EMA(b5); EMA(b6); EMA(b7); } while (0)

    // ---- warm-up: W=64 steps, no stores, double-buffered + sched fences ----
    if (c != 0) {
        p = y + base + (long long)(sm - W) * D4;
        LOADA(); SB();                   //  8 loads in flight
        LOADB(); SB();                   // 16 in flight
        #pragma unroll 1
        for (int g = 0; g < W / 16 - 1; ++g) {   // 3 iters
            EMAA(); LOADA(); SB();       // consume A, re-issue A behind B
            EMAB(); LOADB(); SB();
        }
        EMAA();
        EMAB(); SB();
        // p now == y + base + sm*D4
    } else {
        p = y + base;                    // chunk 0: exact start from h_{-1}=0
    }

    // ---- main: L=128 stored steps, 16 groups of 8, double-buffered ----
    v4* q = out + base + (long long)sm * D4;

#define STA() do {                                              \
        EMA(a0); __builtin_nontemporal_store(h, q + 0 * D4);    \
        EMA(a1); __builtin_nontemporal_store(h, q + 1 * D4);    \
        EMA(a2); __builtin_nontemporal_store(h, q + 2 * D4);    \
        EMA(a3); __builtin_nontemporal_store(h, q + 3 * D4);    \
        EMA(a4); __builtin_nontemporal_store(h, q + 4 * D4);    \
        EMA(a5); __builtin_nontemporal_store(h, q + 5 * D4);    \
        EMA(a6); __builtin_nontemporal_store(h, q + 6 * D4);    \
        EMA(a7); __builtin_nontemporal_store(h, q + 7 * D4);    \
    } while (0)

#define STB() do {                                              \
        EMA(b0); __builtin_nontemporal_store(h, q +  8 * D4);   \
        EMA(b1); __builtin_nontemporal_store(h, q +  9 * D4);   \
        EMA(b2); __builtin_nontemporal_store(h, q + 10 * D4);   \
        EMA(b3); __builtin_nontemporal_store(h, q + 11 * D4);   \
        EMA(b4); __builtin_nontemporal_store(h, q + 12 * D4);   \
        EMA(b5); __builtin_nontemporal_store(h, q + 13 * D4);   \
        EMA(b6); __builtin_nontemporal_store(h, q + 14 * D4);   \
        EMA(b7); __builtin_nontemporal_store(h, q + 15 * D4);   \
    } while (0)

    LOADA(); SB();                       //  8 in flight
    LOADB(); SB();                       // 16 in flight

    #pragma unroll 1
    for (int g = 0; g < L / 16 - 1; ++g) {   // 7 iters
        STA(); LOADA(); SB();            // consume+store A, re-issue A
        STB(); LOADB(); SB();            // consume+store B, re-issue B
        q += 16 * D4;
    }
    // epilogue: consume final two groups, no re-issue
    STA();
    STB();

#undef STB
#undef STA
#undef EMAB
#undef EMAA
#undef EMA
#undef LOADB
#undef LOADA
}

extern "C" void kernel_launch(void* const* d_in, const int* in_sizes, int n_in,
                              void* d_out, int out_size, void* d_ws, size_t ws_size,
                              hipStream_t stream) {
    const v4* y = (const v4*)d_in[0];
    v4* out = (v4*)d_out;

    dim3 block(256, 1, 1);
    dim3 grid(D4 / 256, S / L, B);   // (2, 32, 4) = 256 blocks, 1/CU
    ema_kernel<<<grid, block, 0, stream>>>(y, out);
}

// Round 5
// 236.505 us; speedup vs baseline: 1.0790x; 1.0023x over previous
//
#include <hip/hip_runtime.h>

// EMA h_t = 0.1*y_t + 0.9*h_{t-1} over (B=4, S=4096, D=2048) fp32.
// R8 post-mortem: asm loads into raw registers are structurally unsafe --
// the allocator may insert v_mov copies / live-range splits between the asm
// load and its consumer; a copy executing while the load is in flight
// snapshots garbage (absmax 1.6e16 == address-pattern-as-float). Also vmcnt
// counts stores, which complete OOO vs loads -> final vmcnt(8) was unsound.
// R9: async pipeline via __builtin_amdgcn_global_load_lds (no dest register
// -> no allocator hazard; consumer is a plain LDS read, compiler-managed
// lgkmcnt). Manual counted s_waitcnt vmcnt(8) between DMA and LDS read
// (m201/m218-verified contract: compiler does not auto-drain vmcnt before
// ds_read absent __syncthreads). Ledger is load-only sound: at every WAIT8
// there are 8 LOADS newer than the consumed group; loads return in order,
// so an outstanding old load implies >=9 outstanding -- contradiction.
// Final group waits vmcnt(0). 2 LDS bufs x 8 steps x 4KB = 64KB/block;
// 16 KB DMA in flight per wave (~16 MB chip) >> 2.4 MB latency-BW product.

typedef float v4 __attribute__((ext_vector_type(4)));

constexpr int B  = 4;
constexpr int S  = 4096;
constexpr int D  = 2048;
constexpr int D4 = D / 4;     // 512 vec4 lanes per row
constexpr int L  = 128;       // chunk length  (S/L = 32 chunks)
// warm-up = 8 groups of 8 = 64 steps (0.9^64 ~ 1.2e-3, thr 2.6e-2)

#define SEAL() __builtin_amdgcn_sched_barrier(0)
#define WAIT8() do { asm volatile("s_waitcnt vmcnt(8)" ::: "memory"); SEAL(); } while (0)
#define WAIT0() do { asm volatile("s_waitcnt vmcnt(0)" ::: "memory"); SEAL(); } while (0)

__global__ __launch_bounds__(256, 1) void ema_kernel(const v4* __restrict__ y,
                                                     v4* __restrict__ out) {
    // 64 KiB: [kb=2][step=8][wave=4][lane=64] v4 slots, linear per DMA group
    __shared__ v4 smem[4096];

    const int tid  = threadIdx.x;
    const int wave = tid >> 6;
    const int lane = tid & 63;
    const int d4   = blockIdx.x * blockDim.x + tid;         // 0..D4-1
    const int c    = blockIdx.y;                            // chunk
    const int b    = blockIdx.z;

    const long long base = (long long)b * S * D4 + d4;
    const int sm  = c * L;                                  // first stored step
    const int nwg = (c == 0) ? 0 : 8;                       // warm groups of 8

    const v4* p = y + base + (long long)(sm - 8 * nwg) * D4;
    v4* q = out + base + (long long)sm * D4;

    v4 h = (v4)(0.0f);

    // v4-index of (buffer kb, step s) slot base for this wave (wave-uniform)
#define SLOT(kb, s) ((((kb) * 8 + (s)) * 4 + wave) * 64)

    // one DMA: 64 lanes x 16B, global per-lane addr -> LDS base + lane*16
#define ISSUE1(kb, s) \
    __builtin_amdgcn_global_load_lds(p + (s) * D4, &smem[SLOT(kb, s)], 16, 0, 0)

#define ISSUE(kb) do {                                      \
        ISSUE1(kb, 0); ISSUE1(kb, 1); ISSUE1(kb, 2); ISSUE1(kb, 3); \
        ISSUE1(kb, 4); ISSUE1(kb, 5); ISSUE1(kb, 6); ISSUE1(kb, 7); \
        p += 8 * D4;                                        \
        SEAL();                                             \
    } while (0)

#define EMA1(kb, s) do {                                    \
        v4 x = smem[SLOT(kb, s) + lane];                    \
        h = 0.9f * h + 0.1f * x;                            \
    } while (0)

#define CONS_NS(kb) do {                                    \
        EMA1(kb, 0); EMA1(kb, 1); EMA1(kb, 2); EMA1(kb, 3); \
        EMA1(kb, 4); EMA1(kb, 5); EMA1(kb, 6); EMA1(kb, 7); \
        SEAL();                                             \
    } while (0)

#define EMST1(kb, s) do {                                   \
        v4 x = smem[SLOT(kb, s) + lane];                    \
        h = 0.9f * h + 0.1f * x;                            \
        __builtin_nontemporal_store(h, q + (s) * D4);       \
    } while (0)

#define CONS_ST(kb) do {                                    \
        EMST1(kb, 0); EMST1(kb, 1); EMST1(kb, 2); EMST1(kb, 3); \
        EMST1(kb, 4); EMST1(kb, 5); EMST1(kb, 6); EMST1(kb, 7); \
        q += 8 * D4;                                        \
        SEAL();                                             \
    } while (0)

    // ---- pipeline fill: 2 groups (16 DMAs) in flight ----
    ISSUE(0);
    ISSUE(1);

    // ---- warm-up: 8 unstored groups (c>0 only) ----
    if (c != 0) {
        #pragma unroll 1
        for (int it = 0; it < 4; ++it) {
            WAIT8(); CONS_NS(0); ISSUE(0);
            WAIT8(); CONS_NS(1); ISSUE(1);
        }
    }

    // ---- stored groups g = 0..15 (L = 128 steps) ----
    #pragma unroll 1
    for (int it = 0; it < 7; ++it) {         // consume g=0..13, issue g=2..15
        WAIT8(); CONS_ST(0); ISSUE(0);
        WAIT8(); CONS_ST(1); ISSUE(1);
    }
    WAIT8(); CONS_ST(0);                     // g=14 (8 newer loads exist: g15)
    WAIT0(); CONS_ST(1);                     // g=15 (full drain)

#undef CONS_ST
#undef EMST1
#undef CONS_NS
#undef EMA1
#undef ISSUE
#undef ISSUE1
#undef SLOT
}

extern "C" void kernel_launch(void* const* d_in, const int* in_sizes, int n_in,
                              void* d_out, int out_size, void* d_ws, size_t ws_size,
                              hipStream_t stream) {
    const v4* y = (const v4*)d_in[0];
    v4* out = (v4*)d_out;

    dim3 block(256, 1, 1);
    dim3 grid(D4 / 256, S / L, B);   // (2, 32, 4) = 256 blocks, 1/CU
    ema_kernel<<<grid, block, 0, stream>>>(y, out);
}